// Round 7
// baseline (279.492 us; speedup 1.0000x reference)
//
#include <hip/hip_runtime.h>

// k-th NN distance (k=32 -> 33rd smallest, self excluded), B=16384, D=128.
// R6 resubmit (container infra failure, no signal — same pod pattern as
// R2/R4; identical source): group-max pre-filter (branch per f32x4, not per
// value), block-local LDS candidate buffers with ds-atomics + coalesced dump
// (NSEG=8, SCAP=32), single-buffer A + grid 1024 for 3 blocks/CU occupancy.
// k_stats coalesced.

typedef unsigned short u16;
typedef unsigned int   u32;
typedef __attribute__((ext_vector_type(8))) u16    ushort8;
typedef __attribute__((ext_vector_type(8))) __bf16 bf16x8;
typedef __attribute__((ext_vector_type(4))) float  f32x4;
typedef __attribute__((ext_vector_type(4))) u32    u32x4;

#define NB   16384
#define ND   128
#define NSEG 8            // segments per row = 8 col-eighths (one per block)
#define SCAP 32           // slots per segment (lambda=9, P(>32) ~ 1e-10)
#define NTH  33           // 33rd smallest
#define ZWH  (-2.62f)     // WH quantile z: p~0.0044 -> ~72 cands/row
#define NEGF (-3.0e38f)
#define POSF ( 3.0e38f)

// ---- workspace layout (bytes), total ~22 MB ----
#define OFF_X    ((size_t)0)
#define OFF_NORM (OFF_X    + (size_t)NB * ND * 2)
#define OFF_TACC (OFF_NORM + (size_t)NB * 4)
#define OFF_XBAR (OFF_TACC + (size_t)NB * 4)
#define OFF_SCAL (OFF_XBAR + 512)
#define OFF_CNTS (OFF_SCAL + 256)
#define OFF_CAND (OFF_CNTS + (size_t)NB * NSEG * 4)

static __device__ __forceinline__ u16 f2bf(float f) {
  u32 u = __float_as_uint(f);
  u32 r = u + 0x7FFFu + ((u >> 16) & 1u);
  return (u16)(r >> 16);
}
static __device__ __forceinline__ float bf2f(u16 h) {
  return __uint_as_float(((u32)h) << 16);
}

#if defined(__has_builtin)
#if __has_builtin(__builtin_amdgcn_global_load_lds)
#define HAVE_GLDS 1
#endif
#endif

// Stage 16B/lane: LDS dest = wave-uniform base + lane*16 (linear).
static __device__ __forceinline__ void stage16(const u16* gsrc_lane,
                                               u16* lds_base, int l) {
#ifdef HAVE_GLDS
  __builtin_amdgcn_global_load_lds(
      (const __attribute__((address_space(1))) void*)gsrc_lane,
      (__attribute__((address_space(3))) void*)lds_base, 16, 0, 0);
#else
  *(ushort8*)(lds_base + l * 8) = *(const ushort8*)gsrc_lane;
#endif
}
// Stage 4B/lane (for the column-norm vector).
static __device__ __forceinline__ void stage4(const float* gsrc_lane,
                                              float* lds_base, int l) {
#ifdef HAVE_GLDS
  __builtin_amdgcn_global_load_lds(
      (const __attribute__((address_space(1))) void*)gsrc_lane,
      (__attribute__((address_space(3))) void*)lds_base, 4, 0, 0);
#else
  lds_base[l] = *gsrc_lane;
#endif
}

// ---------------- K1: bf16 convert + norms (+ zero stat accumulators) ----
__global__ void k_prep(const float* __restrict__ x, u16* __restrict__ X,
                       float* __restrict__ norms, float* xbar, float* scal) {
  if (blockIdx.x == 0) {
    int tt = threadIdx.x;
    if (tt < 128) xbar[tt] = 0.f;
    if (tt < 2)   scal[tt] = 0.f;
  }
  int w = threadIdx.x >> 6, l = threadIdx.x & 63;
  int r = blockIdx.x * 4 + w;  // grid 4096
  const float2* xr2 = (const float2*)(x + (size_t)r * ND);
  float2 a = xr2[l];
  u16 h0 = f2bf(a.x), h1 = f2bf(a.y);
  float b0 = bf2f(h0), b1 = bf2f(h1);
  float n = b0 * b0 + b1 * b1;
#pragma unroll
  for (int off = 1; off < 64; off <<= 1) n += __shfl_xor(n, off, 64);
  *(u32*)(X + (size_t)r * ND + 2 * l) = (u32)h0 | ((u32)h1 << 16);
  if (l == 0) norms[r] = n;
}

// ---------------- K2: column sums (x-bar) + sum(n), sum(n^2) -------------
// Coalesced: lanes 0..15 of each 16-thread group cover one row's 128 cols.
__global__ void k_stats(const u16* __restrict__ X, const float* __restrict__ norms,
                        float* xbar, float* scal) {
  __shared__ float xs[16][128];
  __shared__ float red1[256], red2[256];
  int t = threadIdx.x;
  int cg = t & 15;          // col-group: cols cg*8 .. cg*8+7
  int rs = t >> 4;          // row-sub 0..15
  int rbase = blockIdx.x * 256;  // grid 64
  float s[8] = {0.f, 0.f, 0.f, 0.f, 0.f, 0.f, 0.f, 0.f};
  for (int rr = 0; rr < 16; ++rr) {
    int row = rbase + rs + rr * 16;
    ushort8 v = *(const ushort8*)(X + (size_t)row * ND + cg * 8);
#pragma unroll
    for (int u = 0; u < 8; ++u) s[u] += bf2f(v[u]);
  }
#pragma unroll
  for (int u = 0; u < 8; ++u) xs[rs][cg * 8 + u] = s[u];
  float ln = norms[rbase + t];
  red1[t] = ln; red2[t] = ln * ln;
  __syncthreads();
  if (t < 128) {
    float a = 0.f;
    for (int rsub = 0; rsub < 16; ++rsub) a += xs[rsub][t];
    atomicAdd(&xbar[t], a);
  }
  for (int st = 128; st > 0; st >>= 1) {
    if (t < st) { red1[t] += red1[t + st]; red2[t] += red2[t + st]; }
    __syncthreads();
  }
  if (t == 0) { atomicAdd(&scal[0], red1[0]); atomicAdd(&scal[1], red2[0]); }
}

// ---------------- K3: per-row threshold via Wilson-Hilferty chi^2 --------
__global__ void k_thresh(const u16* __restrict__ X, const float* __restrict__ norms,
                         const float* __restrict__ xbar, const float* __restrict__ scal,
                         float* __restrict__ tacc) {
  __shared__ float xb[128];
  int t = threadIdx.x;
  if (t < 128) xb[t] = xbar[t] * (1.0f / NB);
  __syncthreads();
  int r = blockIdx.x * 256 + t;  // grid 64
  float n = norms[r];
  const u16* xr = X + (size_t)r * ND;
  float dot = 0.f;
#pragma unroll
  for (int c8 = 0; c8 < 16; ++c8) {
    ushort8 v = *(const ushort8*)(xr + c8 * 8);
#pragma unroll
    for (int j = 0; j < 8; ++j) dot += bf2f(v[j]) * xb[c8 * 8 + j];
  }
  float nbar = scal[0] * (1.0f / NB);
  float Vn = fmaxf(scal[1] * (1.0f / NB) - nbar * nbar, 0.f);
  float m = n + nbar - 2.f * dot;             // exact E_j[sq_rj]
  float v = Vn + 4.f * n * (nbar / ND);       // Var_j[sq_rj] model
  float nu = 2.f * m * m / v;
  float cc = v / (2.f * m);
  float a1 = 2.f / (9.f * nu);
  float inner = 1.f - a1 + ZWH * sqrtf(a1);
  float tsq = cc * nu * inner * inner * inner;
  tacc[r] = 0.5f * (n - tsq);   // val = acc - nc/2 >= tacc  <=>  sq <= tsq
}

// ---------------- K4: MFMA gram + group-max filter + LDS candidates ------
// grid 1024 = 128 row-strips x 8 col-eighths (XCD-chunked by eighth).
// 4 waves as 2x2 of 64x64 over the 128x128 iter tile; 16 iters.
// Hits -> block-local LDS candidate buffer (ds atomics, rare); coalesced
// dump to global segment (row, q) at the end. 50KB LDS -> 3 blocks/CU.
__global__ __launch_bounds__(256, 3) void k_gram(
    const u16* __restrict__ X, const float* __restrict__ norms,
    const float* __restrict__ tacc, u32* __restrict__ counts,
    float* __restrict__ cands) {
  __shared__ u16 ldsA[32 * 512];               // 32 KB: A tile 128 cols x 128
  __shared__ __align__(16) float nchs[128];    // column norms
  __shared__ u32 cntL[128];                    // per-row hit counters
  __shared__ float candL[128 * SCAP];          // 16 KB candidate slots
  const int bid = blockIdx.x;
  const int logical = (bid & 7) * 128 + (bid >> 3);  // XCD-chunked, bijective
  const int q = logical >> 7, strip = logical & 127;
  const int r0 = strip * 128;
  const int cbase = q * 2048;
  const int t = threadIdx.x, w = t >> 6, l = t & 63;
  const int wr = w & 1, wc = w >> 1;
  const int lm = l & 15, lq = l >> 4;
  const int koff = lq * 8;

  // B fragments (owned rows) -> registers, loaded once.
  bf16x8 bfrag[4][4];  // [k][j]
#pragma unroll
  for (int k = 0; k < 4; ++k)
#pragma unroll
    for (int j = 0; j < 4; ++j)
      bfrag[k][j] = __builtin_bit_cast(bf16x8, *(const ushort8*)(
          X + (size_t)(r0 + (wr * 4 + j) * 16 + lm) * ND + k * 32 + koff));

  int rj[4]; float tj[4];
#pragma unroll
  for (int j = 0; j < 4; ++j) {
    rj[j] = r0 + (wr * 4 + j) * 16 + lm;
    tj[j] = tacc[rj[j]];
  }
  // zero hit counters + stage tile 0
  if (t < 128) cntL[t] = 0u;
  {
#pragma unroll
    for (int s = 0; s < 8; ++s) {
      int g = w * 8 + s;
      stage16(X + (size_t)(cbase + (g & 7) * 16 + lm) * ND + (g >> 3) * 32 + koff,
              &ldsA[g * 512], l);
    }
    if (w < 2) stage4(norms + cbase + w * 64 + l, &nchs[w * 64], l);
  }
  __syncthreads();

  for (int it = 0; it < 16; ++it) {
    const int c0 = cbase + it * 128;
    f32x4 acc[4][4];
#pragma unroll
    for (int i = 0; i < 4; ++i)
#pragma unroll
      for (int j = 0; j < 4; ++j) acc[i][j] = (f32x4){0.f, 0.f, 0.f, 0.f};

#pragma unroll
    for (int k = 0; k < 4; ++k) {
      bf16x8 af[4];
#pragma unroll
      for (int i = 0; i < 4; ++i)
        af[i] = __builtin_bit_cast(bf16x8,
                 *(const ushort8*)(&ldsA[(k * 8 + wc * 4 + i) * 512 + l * 8]));
#pragma unroll
      for (int i = 0; i < 4; ++i)
#pragma unroll
        for (int j = 0; j < 4; ++j)
          acc[i][j] = __builtin_amdgcn_mfma_f32_16x16x32_bf16(af[i], bfrag[k][j], acc[i][j], 0, 0, 0);
    }

    f32x4 nch4[4];
#pragma unroll
    for (int i = 0; i < 4; ++i) {
      nch4[i] = *(const f32x4*)(&nchs[wc * 64 + i * 16 + lq * 4]);
      nch4[i] = nch4[i] * 0.5f;
    }

    // group-max pre-filter: one rare branch per f32x4
    const bool dg = (c0 == r0);
#pragma unroll
    for (int i = 0; i < 4; ++i) {
#pragma unroll
      for (int j = 0; j < 4; ++j) {
        f32x4 val = acc[i][j] - nch4[i];       // = x_c.x_r - n_c/2
        float g01 = fmaxf(val[0], val[1]);
        float g23 = fmaxf(val[2], val[3]);
        if (fmaxf(g01, g23) >= tj[j]) {        // rare (hit rate ~1.7%/group)
          int rloc = (wr * 4 + j) * 16 + lm;
#pragma unroll
          for (int v = 0; v < 4; ++v) {
            bool p = (val[v] >= tj[j]);
            if (dg) p = p && ((c0 + wc * 64 + i * 16 + lq * 4 + v) != rj[j]);
            if (p) {
              u32 pos = atomicAdd(&cntL[rloc], 1u);
              if (pos < SCAP) candL[rloc * SCAP + pos] = val[v];
            }
          }
        }
      }
    }

    if (it + 1 < 16) {
      __syncthreads();   // all waves done reading ldsA/nchs
      const int c1 = c0 + 128;
#pragma unroll
      for (int s = 0; s < 8; ++s) {
        int g = w * 8 + s;
        stage16(X + (size_t)(c1 + (g & 7) * 16 + lm) * ND + (g >> 3) * 32 + koff,
                &ldsA[g * 512], l);
      }
      if (w < 2) stage4(norms + c1 + w * 64 + l, &nchs[w * 64], l);
      __syncthreads();   // staged tile ready
    }
  }

  __syncthreads();  // candL/cntL complete
  // coalesced dump: counts + candidate slots for this (row, q) segment
  if (t < 128) counts[(size_t)(r0 + t) * NSEG + q] = cntL[t];
#pragma unroll
  for (int u = 0; u < 16; ++u) {
    int idx = t + u * 256;             // 0..4095
    int row = idx >> 5, s = idx & 31;
    cands[((size_t)(r0 + row) * NSEG + q) * SCAP + s] = candL[idx];
  }
}

// ---------------- K5: per-row exact 33rd smallest among candidates --------
__global__ void k_select(const u32* __restrict__ counts, const float* __restrict__ cands,
                         const float* __restrict__ norms, float* __restrict__ out) {
  int w = threadIdx.x >> 6, l = threadIdx.x & 63;
  int r = blockIdx.x * 4 + w;  // grid 4096
  u32 myc = (l < NSEG) ? counts[(size_t)r * NSEG + l] : 0u;
  u32 tot = myc, mx = myc;
#pragma unroll
  for (int off = 1; off < 64; off <<= 1) {
    tot += __shfl_xor(tot, off, 64);
    u32 o = (u32)__shfl_xor((int)mx, off, 64);
    mx = mx > o ? mx : o;
  }
  if (tot < NTH || mx > SCAP) return;  // fallback kernel owns this row

  const float* base = cands + (size_t)r * (NSEG * SCAP);
  float v0, v1, v2, v3;
#define LOADV(e, dst)                                        \
  {                                                          \
    int f = l + 64 * e;                                      \
    int sg = f >> 5, sl = f & 31;                            \
    u32 c = (u32)__shfl((int)myc, sg, 64);                   \
    float x = base[f];                                       \
    dst = (sl < (int)c) ? x : NEGF;                          \
  }
  LOADV(0, v0) LOADV(1, v1) LOADV(2, v2) LOADV(3, v3)
#undef LOADV

  float last = NEGF;
  for (int e = 0; e < NTH; ++e) {  // bigger val = closer; extract-max x33
    float m = fmaxf(fmaxf(v0, v1), fmaxf(v2, v3));
#pragma unroll
    for (int off = 1; off < 64; off <<= 1) m = fmaxf(m, __shfl_xor(m, off, 64));
    bool mine = (v0 == m) || (v1 == m) || (v2 == m) || (v3 == m);
    unsigned long long bal = __ballot(mine);
    int owner = __ffsll(bal) - 1;
    if (l == owner) {
      if      (v0 == m) v0 = NEGF;
      else if (v1 == m) v1 = NEGF;
      else if (v2 == m) v2 = NEGF;
      else              v3 = NEGF;
    }
    last = m;
  }
  out[r] = sqrtf(fmaxf(norms[r] - 2.f * last, 0.f));  // sq = n_r - 2*val
}

// ---------------- K6: exact brute-force fallback (expected ~0 rows) -------
__global__ void k_fallback(const u32* __restrict__ counts, const u16* __restrict__ X,
                           const float* __restrict__ norms, float* __restrict__ out) {
  __shared__ float sq[NB];     // 64 KB
  __shared__ float xr[ND];
  __shared__ float rmin[256];
  __shared__ int   ridx[256];
  __shared__ int   nbad;
  __shared__ int   badlist[256];
  int t = threadIdx.x;
  if (t == 0) nbad = 0;
  __syncthreads();
  int r = blockIdx.x * 256 + t;   // grid 64: covers NB exactly
  u32 tot = 0, mx = 0;
#pragma unroll
  for (int s4 = 0; s4 < 2; ++s4) {
    u32x4 c = *(const u32x4*)(counts + (size_t)r * NSEG + s4 * 4);
#pragma unroll
    for (int u = 0; u < 4; ++u) { tot += c[u]; mx = c[u] > mx ? c[u] : mx; }
  }
  if (tot < NTH || mx > SCAP) { int p = atomicAdd(&nbad, 1); badlist[p] = r; }
  __syncthreads();
  int nb = nbad;
  for (int ii = 0; ii < nb; ++ii) {
    int rr = badlist[ii];
    if (t < 128) xr[t] = bf2f(X[(size_t)rr * ND + t]);
    __syncthreads();
    float n_r = norms[rr];
    for (int jj = 0; jj < 64; ++jj) {
      int j = t + 256 * jj;
      const u16* xj = X + (size_t)j * ND;
      float dot = 0.f;
#pragma unroll
      for (int c8 = 0; c8 < 16; ++c8) {
        ushort8 vv = *(const ushort8*)(xj + c8 * 8);
#pragma unroll
        for (int u = 0; u < 8; ++u) dot += bf2f(vv[u]) * xr[c8 * 8 + u];
      }
      sq[j] = (j == rr) ? POSF : fmaxf(n_r + norms[j] - 2.f * dot, 0.f);
    }
    __syncthreads();
    float last = 0.f;
    for (int e = 0; e < NTH; ++e) {
      float lm = POSF; int li = -1;
      for (int jj = 0; jj < 64; ++jj) {
        int j = t + 256 * jj;
        float s = sq[j];
        if (s < lm) { lm = s; li = j; }
      }
      rmin[t] = lm; ridx[t] = li;
      __syncthreads();
      if (t == 0) {
        float gm = POSF; int gi = -1;
        for (int u = 0; u < 256; ++u)
          if (rmin[u] < gm) { gm = rmin[u]; gi = ridx[u]; }
        sq[gi] = POSF;
        rmin[0] = gm;
      }
      __syncthreads();
      last = rmin[0];
      __syncthreads();
    }
    if (t == 0) out[rr] = sqrtf(fmaxf(last, 0.f));
    __syncthreads();
  }
}

extern "C" void kernel_launch(void* const* d_in, const int* in_sizes, int n_in,
                              void* d_out, int out_size, void* d_ws, size_t ws_size,
                              hipStream_t stream) {
  const float* x = (const float*)d_in[0];
  float* out = (float*)d_out;
  char* ws = (char*)d_ws;
  u16*   X     = (u16*)  (ws + OFF_X);
  float* norms = (float*)(ws + OFF_NORM);
  float* tacc  = (float*)(ws + OFF_TACC);
  float* xbar  = (float*)(ws + OFF_XBAR);
  float* scal  = (float*)(ws + OFF_SCAL);
  u32*   cnts  = (u32*)  (ws + OFF_CNTS);
  float* cands = (float*)(ws + OFF_CAND);

  k_prep    <<<4096, 256, 0, stream>>>(x, X, norms, xbar, scal);
  k_stats   <<<64,   256, 0, stream>>>(X, norms, xbar, scal);
  k_thresh  <<<64,   256, 0, stream>>>(X, norms, xbar, scal, tacc);
  k_gram    <<<1024, 256, 0, stream>>>(X, norms, tacc, cnts, cands);
  k_select  <<<4096, 256, 0, stream>>>(cnts, cands, norms, out);
  k_fallback<<<64,   256, 0, stream>>>(cnts, X, norms, out);
}

// Round 8
// 235.760 us; speedup vs baseline: 1.1855x; 1.1855x over previous
//
#include <hip/hip_runtime.h>

// k-th NN distance (k=32 -> 33rd smallest, self excluded), B=16384, D=128.
// R8: k_gram barrier-free K-loop — A-fragments loaded DIRECTLY global->reg
// (no LDS staging, no __syncthreads in the loop); B fragments in registers;
// group-max pre-filter; block-local LDS candidate buffer (ds-atomics) with
// coalesced dump. Grid 1024, XCD-chunked. Other kernels unchanged from R7.

typedef unsigned short u16;
typedef unsigned int   u32;
typedef __attribute__((ext_vector_type(8))) u16    ushort8;
typedef __attribute__((ext_vector_type(8))) __bf16 bf16x8;
typedef __attribute__((ext_vector_type(4))) float  f32x4;
typedef __attribute__((ext_vector_type(4))) u32    u32x4;

#define NB   16384
#define ND   128
#define NSEG 8            // segments per row = 8 col-eighths (one per block)
#define SCAP 32           // slots per segment (lambda=9, P(>32) ~ 1e-10)
#define NTH  33           // 33rd smallest
#define ZWH  (-2.62f)     // WH quantile z: p~0.0044 -> ~72 cands/row
#define NEGF (-3.0e38f)
#define POSF ( 3.0e38f)

// ---- workspace layout (bytes), total ~22 MB ----
#define OFF_X    ((size_t)0)
#define OFF_NORM (OFF_X    + (size_t)NB * ND * 2)
#define OFF_TACC (OFF_NORM + (size_t)NB * 4)
#define OFF_XBAR (OFF_TACC + (size_t)NB * 4)
#define OFF_SCAL (OFF_XBAR + 512)
#define OFF_CNTS (OFF_SCAL + 256)
#define OFF_CAND (OFF_CNTS + (size_t)NB * NSEG * 4)

static __device__ __forceinline__ u16 f2bf(float f) {
  u32 u = __float_as_uint(f);
  u32 r = u + 0x7FFFu + ((u >> 16) & 1u);
  return (u16)(r >> 16);
}
static __device__ __forceinline__ float bf2f(u16 h) {
  return __uint_as_float(((u32)h) << 16);
}

// ---------------- K1: bf16 convert + norms (+ zero stat accumulators) ----
__global__ void k_prep(const float* __restrict__ x, u16* __restrict__ X,
                       float* __restrict__ norms, float* xbar, float* scal) {
  if (blockIdx.x == 0) {
    int tt = threadIdx.x;
    if (tt < 128) xbar[tt] = 0.f;
    if (tt < 2)   scal[tt] = 0.f;
  }
  int w = threadIdx.x >> 6, l = threadIdx.x & 63;
  int r = blockIdx.x * 4 + w;  // grid 4096
  const float2* xr2 = (const float2*)(x + (size_t)r * ND);
  float2 a = xr2[l];
  u16 h0 = f2bf(a.x), h1 = f2bf(a.y);
  float b0 = bf2f(h0), b1 = bf2f(h1);
  float n = b0 * b0 + b1 * b1;
#pragma unroll
  for (int off = 1; off < 64; off <<= 1) n += __shfl_xor(n, off, 64);
  *(u32*)(X + (size_t)r * ND + 2 * l) = (u32)h0 | ((u32)h1 << 16);
  if (l == 0) norms[r] = n;
}

// ---------------- K2: column sums (x-bar) + sum(n), sum(n^2) -------------
__global__ void k_stats(const u16* __restrict__ X, const float* __restrict__ norms,
                        float* xbar, float* scal) {
  __shared__ float xs[16][128];
  __shared__ float red1[256], red2[256];
  int t = threadIdx.x;
  int cg = t & 15;          // col-group: cols cg*8 .. cg*8+7
  int rs = t >> 4;          // row-sub 0..15
  int rbase = blockIdx.x * 256;  // grid 64
  float s[8] = {0.f, 0.f, 0.f, 0.f, 0.f, 0.f, 0.f, 0.f};
  for (int rr = 0; rr < 16; ++rr) {
    int row = rbase + rs + rr * 16;
    ushort8 v = *(const ushort8*)(X + (size_t)row * ND + cg * 8);
#pragma unroll
    for (int u = 0; u < 8; ++u) s[u] += bf2f(v[u]);
  }
#pragma unroll
  for (int u = 0; u < 8; ++u) xs[rs][cg * 8 + u] = s[u];
  float ln = norms[rbase + t];
  red1[t] = ln; red2[t] = ln * ln;
  __syncthreads();
  if (t < 128) {
    float a = 0.f;
    for (int rsub = 0; rsub < 16; ++rsub) a += xs[rsub][t];
    atomicAdd(&xbar[t], a);
  }
  for (int st = 128; st > 0; st >>= 1) {
    if (t < st) { red1[t] += red1[t + st]; red2[t] += red2[t + st]; }
    __syncthreads();
  }
  if (t == 0) { atomicAdd(&scal[0], red1[0]); atomicAdd(&scal[1], red2[0]); }
}

// ---------------- K3: per-row threshold via Wilson-Hilferty chi^2 --------
__global__ void k_thresh(const u16* __restrict__ X, const float* __restrict__ norms,
                         const float* __restrict__ xbar, const float* __restrict__ scal,
                         float* __restrict__ tacc) {
  __shared__ float xb[128];
  int t = threadIdx.x;
  if (t < 128) xb[t] = xbar[t] * (1.0f / NB);
  __syncthreads();
  int r = blockIdx.x * 256 + t;  // grid 64
  float n = norms[r];
  const u16* xr = X + (size_t)r * ND;
  float dot = 0.f;
#pragma unroll
  for (int c8 = 0; c8 < 16; ++c8) {
    ushort8 v = *(const ushort8*)(xr + c8 * 8);
#pragma unroll
    for (int j = 0; j < 8; ++j) dot += bf2f(v[j]) * xb[c8 * 8 + j];
  }
  float nbar = scal[0] * (1.0f / NB);
  float Vn = fmaxf(scal[1] * (1.0f / NB) - nbar * nbar, 0.f);
  float m = n + nbar - 2.f * dot;             // exact E_j[sq_rj]
  float v = Vn + 4.f * n * (nbar / ND);       // Var_j[sq_rj] model
  float nu = 2.f * m * m / v;
  float cc = v / (2.f * m);
  float a1 = 2.f / (9.f * nu);
  float inner = 1.f - a1 + ZWH * sqrtf(a1);
  float tsq = cc * nu * inner * inner * inner;
  tacc[r] = 0.5f * (n - tsq);   // val = acc - nc/2 >= tacc  <=>  sq <= tsq
}

// ---------------- K4: MFMA gram, barrier-free, direct-reg A --------------
// grid 1024 = 128 row-strips x 8 col-eighths (XCD-chunked by eighth).
// 4 waves as 2x2 of 64x64 over the 128x128 iter tile; 16 iters.
// A-fragments: global->reg per k-step (16 rows x 64B pattern, L2-hit).
// No __syncthreads in the loop -> waves free-run, compiler pipelines loads.
__global__ __launch_bounds__(256) void k_gram(
    const u16* __restrict__ X, const float* __restrict__ norms,
    const float* __restrict__ tacc, u32* __restrict__ counts,
    float* __restrict__ cands) {
  __shared__ u32 cntL[128];                    // per-row hit counters
  __shared__ float candL[128 * SCAP];          // 16 KB candidate slots
  const int bid = blockIdx.x;
  const int logical = (bid & 7) * 128 + (bid >> 3);  // XCD-chunked, bijective
  const int q = logical >> 7, strip = logical & 127;
  const int r0 = strip * 128;
  const int cbase = q * 2048;
  const int t = threadIdx.x, w = t >> 6, l = t & 63;
  const int wr = w & 1, wc = w >> 1;
  const int lm = l & 15, lq = l >> 4;
  const int koff = lq * 8;

  // B fragments (owned rows) -> registers, loaded once.
  bf16x8 bfrag[4][4];  // [k][j]
#pragma unroll
  for (int k = 0; k < 4; ++k)
#pragma unroll
    for (int j = 0; j < 4; ++j)
      bfrag[k][j] = __builtin_bit_cast(bf16x8, *(const ushort8*)(
          X + (size_t)(r0 + (wr * 4 + j) * 16 + lm) * ND + k * 32 + koff));

  int rj[4]; float tj[4];
#pragma unroll
  for (int j = 0; j < 4; ++j) {
    rj[j] = r0 + (wr * 4 + j) * 16 + lm;
    tj[j] = tacc[rj[j]];
  }
  if (t < 128) cntL[t] = 0u;
  __syncthreads();   // cntL ready (only barrier before the dump)

  // per-lane A base: row (cbase + wc*64 + lm), k-chunk koff
  const u16* abase = X + (size_t)(cbase + wc * 64 + lm) * ND + koff;

  for (int it = 0; it < 16; ++it) {
    const int c0 = cbase + it * 128;
    const u16* ait = abase + (size_t)it * 128 * ND;

    f32x4 acc[4][4];
#pragma unroll
    for (int i = 0; i < 4; ++i)
#pragma unroll
      for (int j = 0; j < 4; ++j) acc[i][j] = (f32x4){0.f, 0.f, 0.f, 0.f};

#pragma unroll
    for (int k = 0; k < 4; ++k) {
      bf16x8 af[4];
#pragma unroll
      for (int i = 0; i < 4; ++i)
        af[i] = __builtin_bit_cast(bf16x8, *(const ushort8*)(
            ait + (size_t)(i * 16) * ND + k * 32));
#pragma unroll
      for (int i = 0; i < 4; ++i)
#pragma unroll
        for (int j = 0; j < 4; ++j)
          acc[i][j] = __builtin_amdgcn_mfma_f32_16x16x32_bf16(af[i], bfrag[k][j], acc[i][j], 0, 0, 0);
    }

    f32x4 nch4[4];
#pragma unroll
    for (int i = 0; i < 4; ++i) {
      nch4[i] = *(const f32x4*)(norms + c0 + wc * 64 + i * 16 + lq * 4);
      nch4[i] = nch4[i] * 0.5f;
    }

    // group-max pre-filter: one rare branch per f32x4
    const bool dg = (c0 == r0);
#pragma unroll
    for (int i = 0; i < 4; ++i) {
#pragma unroll
      for (int j = 0; j < 4; ++j) {
        f32x4 val = acc[i][j] - nch4[i];       // = x_c.x_r - n_c/2
        float g01 = fmaxf(val[0], val[1]);
        float g23 = fmaxf(val[2], val[3]);
        if (fmaxf(g01, g23) >= tj[j]) {        // rare (~1.7% of groups)
          int rloc = (wr * 4 + j) * 16 + lm;
#pragma unroll
          for (int v = 0; v < 4; ++v) {
            bool p = (val[v] >= tj[j]);
            if (dg) p = p && ((c0 + wc * 64 + i * 16 + lq * 4 + v) != rj[j]);
            if (p) {
              u32 pos = atomicAdd(&cntL[rloc], 1u);
              if (pos < SCAP) candL[rloc * SCAP + pos] = val[v];
            }
          }
        }
      }
    }
  }

  __syncthreads();  // candL/cntL complete
  // coalesced dump: counts + candidate slots for this (row, q) segment
  if (t < 128) counts[(size_t)(r0 + t) * NSEG + q] = cntL[t];
#pragma unroll
  for (int u = 0; u < 16; ++u) {
    int idx = t + u * 256;             // 0..4095
    int row = idx >> 5, s = idx & 31;
    cands[((size_t)(r0 + row) * NSEG + q) * SCAP + s] = candL[idx];
  }
}

// ---------------- K5: per-row exact 33rd smallest among candidates --------
__global__ void k_select(const u32* __restrict__ counts, const float* __restrict__ cands,
                         const float* __restrict__ norms, float* __restrict__ out) {
  int w = threadIdx.x >> 6, l = threadIdx.x & 63;
  int r = blockIdx.x * 4 + w;  // grid 4096
  u32 myc = (l < NSEG) ? counts[(size_t)r * NSEG + l] : 0u;
  u32 tot = myc, mx = myc;
#pragma unroll
  for (int off = 1; off < 64; off <<= 1) {
    tot += __shfl_xor(tot, off, 64);
    u32 o = (u32)__shfl_xor((int)mx, off, 64);
    mx = mx > o ? mx : o;
  }
  if (tot < NTH || mx > SCAP) return;  // fallback kernel owns this row

  const float* base = cands + (size_t)r * (NSEG * SCAP);
  float v0, v1, v2, v3;
#define LOADV(e, dst)                                        \
  {                                                          \
    int f = l + 64 * e;                                      \
    int sg = f >> 5, sl = f & 31;                            \
    u32 c = (u32)__shfl((int)myc, sg, 64);                   \
    float x = base[f];                                       \
    dst = (sl < (int)c) ? x : NEGF;                          \
  }
  LOADV(0, v0) LOADV(1, v1) LOADV(2, v2) LOADV(3, v3)
#undef LOADV

  float last = NEGF;
  for (int e = 0; e < NTH; ++e) {  // bigger val = closer; extract-max x33
    float m = fmaxf(fmaxf(v0, v1), fmaxf(v2, v3));
#pragma unroll
    for (int off = 1; off < 64; off <<= 1) m = fmaxf(m, __shfl_xor(m, off, 64));
    bool mine = (v0 == m) || (v1 == m) || (v2 == m) || (v3 == m);
    unsigned long long bal = __ballot(mine);
    int owner = __ffsll(bal) - 1;
    if (l == owner) {
      if      (v0 == m) v0 = NEGF;
      else if (v1 == m) v1 = NEGF;
      else if (v2 == m) v2 = NEGF;
      else              v3 = NEGF;
    }
    last = m;
  }
  out[r] = sqrtf(fmaxf(norms[r] - 2.f * last, 0.f));  // sq = n_r - 2*val
}

// ---------------- K6: exact brute-force fallback (expected ~0 rows) -------
__global__ void k_fallback(const u32* __restrict__ counts, const u16* __restrict__ X,
                           const float* __restrict__ norms, float* __restrict__ out) {
  __shared__ float sq[NB];     // 64 KB
  __shared__ float xr[ND];
  __shared__ float rmin[256];
  __shared__ int   ridx[256];
  __shared__ int   nbad;
  __shared__ int   badlist[256];
  int t = threadIdx.x;
  if (t == 0) nbad = 0;
  __syncthreads();
  int r = blockIdx.x * 256 + t;   // grid 64: covers NB exactly
  u32 tot = 0, mx = 0;
#pragma unroll
  for (int s4 = 0; s4 < 2; ++s4) {
    u32x4 c = *(const u32x4*)(counts + (size_t)r * NSEG + s4 * 4);
#pragma unroll
    for (int u = 0; u < 4; ++u) { tot += c[u]; mx = c[u] > mx ? c[u] : mx; }
  }
  if (tot < NTH || mx > SCAP) { int p = atomicAdd(&nbad, 1); badlist[p] = r; }
  __syncthreads();
  int nb = nbad;
  for (int ii = 0; ii < nb; ++ii) {
    int rr = badlist[ii];
    if (t < 128) xr[t] = bf2f(X[(size_t)rr * ND + t]);
    __syncthreads();
    float n_r = norms[rr];
    for (int jj = 0; jj < 64; ++jj) {
      int j = t + 256 * jj;
      const u16* xj = X + (size_t)j * ND;
      float dot = 0.f;
#pragma unroll
      for (int c8 = 0; c8 < 16; ++c8) {
        ushort8 vv = *(const ushort8*)(xj + c8 * 8);
#pragma unroll
        for (int u = 0; u < 8; ++u) dot += bf2f(vv[u]) * xr[c8 * 8 + u];
      }
      sq[j] = (j == rr) ? POSF : fmaxf(n_r + norms[j] - 2.f * dot, 0.f);
    }
    __syncthreads();
    float last = 0.f;
    for (int e = 0; e < NTH; ++e) {
      float lm = POSF; int li = -1;
      for (int jj = 0; jj < 64; ++jj) {
        int j = t + 256 * jj;
        float s = sq[j];
        if (s < lm) { lm = s; li = j; }
      }
      rmin[t] = lm; ridx[t] = li;
      __syncthreads();
      if (t == 0) {
        float gm = POSF; int gi = -1;
        for (int u = 0; u < 256; ++u)
          if (rmin[u] < gm) { gm = rmin[u]; gi = ridx[u]; }
        sq[gi] = POSF;
        rmin[0] = gm;
      }
      __syncthreads();
      last = rmin[0];
      __syncthreads();
    }
    if (t == 0) out[rr] = sqrtf(fmaxf(last, 0.f));
    __syncthreads();
  }
}

extern "C" void kernel_launch(void* const* d_in, const int* in_sizes, int n_in,
                              void* d_out, int out_size, void* d_ws, size_t ws_size,
                              hipStream_t stream) {
  const float* x = (const float*)d_in[0];
  float* out = (float*)d_out;
  char* ws = (char*)d_ws;
  u16*   X     = (u16*)  (ws + OFF_X);
  float* norms = (float*)(ws + OFF_NORM);
  float* tacc  = (float*)(ws + OFF_TACC);
  float* xbar  = (float*)(ws + OFF_XBAR);
  float* scal  = (float*)(ws + OFF_SCAL);
  u32*   cnts  = (u32*)  (ws + OFF_CNTS);
  float* cands = (float*)(ws + OFF_CAND);

  k_prep    <<<4096, 256, 0, stream>>>(x, X, norms, xbar, scal);
  k_stats   <<<64,   256, 0, stream>>>(X, norms, xbar, scal);
  k_thresh  <<<64,   256, 0, stream>>>(X, norms, xbar, scal, tacc);
  k_gram    <<<1024, 256, 0, stream>>>(X, norms, tacc, cnts, cands);
  k_select  <<<4096, 256, 0, stream>>>(cnts, cands, norms, out);
  k_fallback<<<64,   256, 0, stream>>>(cnts, X, norms, out);
}